// Round 1
// baseline (444.558 us; speedup 1.0000x reference)
//
#include <hip/hip_runtime.h>

#define T_  8192
#define E_  256
#define BS_ 128

typedef __attribute__((ext_vector_type(8))) short bf16x8;
typedef __attribute__((ext_vector_type(4))) float f32x4;

__device__ __forceinline__ unsigned short f2bf(float x) {
    unsigned int u = __float_as_uint(x);
    u += 0x7fffu + ((u >> 16) & 1u);           // round-to-nearest-even
    return (unsigned short)(u >> 16);
}

__device__ __forceinline__ bf16x8 pack8(f32x4 a, f32x4 b) {
    bf16x8 r;
    r[0] = (short)f2bf(a[0]); r[1] = (short)f2bf(a[1]);
    r[2] = (short)f2bf(a[2]); r[3] = (short)f2bf(a[3]);
    r[4] = (short)f2bf(b[0]); r[5] = (short)f2bf(b[1]);
    r[6] = (short)f2bf(b[2]); r[7] = (short)f2bf(b[3]);
    return r;
}

// Raw barrier: orders LDS only (s_waitcnt lgkmcnt(0) + s_barrier).
// Unlike __syncthreads it does NOT drain vmcnt, so global loads (V prefetch,
// Q fragments) and stores (A, fire-and-forget) stay in flight across it.
__device__ __forceinline__ void lds_barrier() {
    asm volatile("s_waitcnt lgkmcnt(0)" ::: "memory");
    __builtin_amdgcn_s_barrier();
}

// Fused diag-block attention: one WG per (batch, block) tile, 512 threads = 8 waves.
// Phases: stage K (bf16, swizzled, 64 KB LDS) -> QK^T -> prefetch V ks=0,1 ->
// softmax -> store A (fp32, nontemporal, never read back) -> lds_barrier ->
// P bf16 -> LDS (32 KB, reuses K region, A-operand layout) -> lds_barrier ->
// PV with V read STRAIGHT from global (wave w owns cols [32w,32w+32), so every
// V byte is read exactly once per WG; k-steps 2,3 prefetched at distance 2).
__global__ __launch_bounds__(512, 4) void dba_fused(
        const float* __restrict__ Qg, const float* __restrict__ Kg,
        const float* __restrict__ Vg, float* __restrict__ Ag,
        float* __restrict__ Og)
{
    __shared__ unsigned short Sm[BS_ * E_];   // 64 KB: K[128][256] bf16; later P[128][128] bf16 in low 32 KB

    const int tid  = threadIdx.x;
    const int lane = tid & 63;
    const int w    = tid >> 6;     // wave 0..7
    const int cl   = lane & 15;    // col (C layout) / m (A layout) / n (B layout)
    const int g    = lane >> 4;    // quad group 0..3
    const int bi   = blockIdx.x >> 6;
    const int ni   = blockIdx.x & 63;
    const int base  = (bi * T_ + ni * BS_) * E_;
    const int abase = (bi * T_ + ni * BS_) * BS_;
    const int vcol  = w * 32 + cl;             // this wave's O/V column base

    // Q fragment for ks=0, issued before K staging (raw barrier won't drain it)
    const float* qp = Qg + base + (w * 16 + cl) * E_;
    f32x4 q0 = __builtin_nontemporal_load((const f32x4*)(qp + g * 8));
    f32x4 q1 = __builtin_nontemporal_load((const f32x4*)(qp + g * 8 + 4));

    // ---- stage K: fp32 global -> bf16 LDS, 16B-chunk XOR swizzle by (row&15) ----
    {
        const int c4   = lane * 4;            // col 0..252 step 4
        const int chnk = c4 >> 3;
        const int klow = c4 & 7;              // 0 or 4
        #pragma unroll 8
        for (int i = 0; i < 16; ++i) {
            const int n = i * 8 + w;          // key row 0..127
            f32x4 kv = __builtin_nontemporal_load((const f32x4*)(Kg + base + n * E_ + c4));
            const int cp = chnk ^ (n & 15);
            uint2 pk;
            pk.x = (unsigned)f2bf(kv[0]) | ((unsigned)f2bf(kv[1]) << 16);
            pk.y = (unsigned)f2bf(kv[2]) | ((unsigned)f2bf(kv[3]) << 16);
            *(uint2*)&Sm[n * E_ + cp * 8 + klow] = pk;
        }
    }
    lds_barrier();

    // ---- S = Q K^T via mfma_f32_16x16x32_bf16; wave w: 1 row-tile x 8 col-tiles ----
    f32x4 acc[8];
    #pragma unroll
    for (int nt = 0; nt < 8; ++nt) acc[nt] = (f32x4){0.f, 0.f, 0.f, 0.f};

    for (int ks = 0; ks < 8; ++ks) {          // contraction: 8 steps of 32
        bf16x8 aq = pack8(q0, q1);
        if (ks < 7) {
            const int kn = (ks + 1) * 32 + g * 8;
            q0 = __builtin_nontemporal_load((const f32x4*)(qp + kn));
            q1 = __builtin_nontemporal_load((const f32x4*)(qp + kn + 4));
        }
        #pragma unroll
        for (int nt = 0; nt < 8; ++nt) {
            const int n  = nt * 16 + cl;      // key row
            const int cp = (ks * 4 + g) ^ cl;
            bf16x8 bk = *(const bf16x8*)&Sm[n * E_ + cp * 8];
            acc[nt] = __builtin_amdgcn_mfma_f32_16x16x32_bf16(aq, bk, acc[nt], 0, 0, 0);
        }
    }

    // ---- prefetch V k-steps 0,1 (32 coalesced dwords): HBM latency hides under
    //      softmax + A-store + P-LDS write + two barriers ----
    float vb[2][16];
    #pragma unroll
    for (int t = 0; t < 16; ++t)
        vb[0][t] = __builtin_nontemporal_load(
            Vg + base + (g * 8 + (t & 7)) * E_ + vcol + (t >> 3) * 16);
    #pragma unroll
    for (int t = 0; t < 16; ++t)
        vb[1][t] = __builtin_nontemporal_load(
            Vg + base + (32 + g * 8 + (t & 7)) * E_ + vcol + (t >> 3) * 16);

    // ---- mask + softmax. C layout: col = 16*nt + cl, row = 16*w + 4*g + r ----
    const float scale = 0.0625f;               // 1/sqrt(256)
    const float L2E   = 1.4426950408889634f;
    #pragma unroll
    for (int r = 0; r < 4; ++r) {
        const int q = w * 16 + g * 4 + r;      // local query row
        float m = -__builtin_inff();
        #pragma unroll
        for (int nt = 0; nt < 8; ++nt) {
            const int c = nt * 16 + cl;
            float z = acc[nt][r] * scale;
            z = (c > q) ? -__builtin_inff() : z;
            acc[nt][r] = z;
            m = fmaxf(m, z);
        }
        m = fmaxf(m, __shfl_xor(m, 1));
        m = fmaxf(m, __shfl_xor(m, 2));
        m = fmaxf(m, __shfl_xor(m, 4));
        m = fmaxf(m, __shfl_xor(m, 8));
        float s = 0.f;
        #pragma unroll
        for (int nt = 0; nt < 8; ++nt) {
            const float p = exp2f((acc[nt][r] - m) * L2E);
            acc[nt][r] = p;
            s += p;
        }
        s += __shfl_xor(s, 1);
        s += __shfl_xor(s, 2);
        s += __shfl_xor(s, 4);
        s += __shfl_xor(s, 8);
        const float rinv = __builtin_amdgcn_rcpf(s);
        #pragma unroll
        for (int nt = 0; nt < 8; ++nt)
            acc[nt][r] *= rinv;
    }

    // ---- store A (fp32, mandatory output #2). Fire-and-forget: nothing reads it
    //      back, and raw barriers never drain the store acks. ----
    #pragma unroll
    for (int nt = 0; nt < 8; ++nt)
        #pragma unroll
        for (int r = 0; r < 4; ++r)
            __builtin_nontemporal_store(acc[nt][r],
                Ag + abase + (w * 16 + g * 4 + r) * BS_ + nt * 16 + cl);

    lds_barrier();   // all waves done reading K-LDS; safe to overwrite with P

    // ---- P (bf16) -> LDS [q][k], same 16B-chunk XOR swizzle by (q&15).
    //      Write: lane (cl,g,r,nt) holds P[q=16w+4g+r][k=16nt+cl]; the per-g XOR
    //      spreads chunks so the b16 writes are only 2-way (free). ----
    #pragma unroll
    for (int nt = 0; nt < 8; ++nt)
        #pragma unroll
        for (int r = 0; r < 4; ++r) {
            const int q = w * 16 + g * 4 + r;
            const int k = nt * 16 + cl;
            Sm[q * BS_ + (((k >> 3) ^ (g * 4 + r)) * 8) + (k & 7)] = f2bf(acc[nt][r]);
        }

    lds_barrier();   // P visible WG-wide

    // ---- O = P V: wave w owns output cols [32w,32w+32), all 8 q-row tiles.
    //      A-operand from P-LDS (swizzled b128 reads), B-operand = V straight
    //      from global (each byte read exactly once per WG). ----
    f32x4 acc2[8][2];
    #pragma unroll
    for (int mt = 0; mt < 8; ++mt) {
        acc2[mt][0] = (f32x4){0.f, 0.f, 0.f, 0.f};
        acc2[mt][1] = (f32x4){0.f, 0.f, 0.f, 0.f};
    }

    #pragma unroll
    for (int ks = 0; ks < 4; ++ks) {
        bf16x8 bv0, bv1;
        #pragma unroll
        for (int j = 0; j < 8; ++j) {
            bv0[j] = (short)f2bf(vb[ks & 1][j]);
            bv1[j] = (short)f2bf(vb[ks & 1][8 + j]);
        }
        if (ks < 2) {   // prefetch k-steps 2,3 into the buffer just consumed
            #pragma unroll
            for (int t = 0; t < 16; ++t)
                vb[ks & 1][t] = __builtin_nontemporal_load(
                    Vg + base + ((ks + 2) * 32 + g * 8 + (t & 7)) * E_ + vcol + (t >> 3) * 16);
        }
        #pragma unroll
        for (int mt = 0; mt < 8; ++mt) {
            const int q = mt * 16 + cl;        // P row; q&15 == cl
            const bf16x8 pa = *(const bf16x8*)&Sm[q * BS_ + (((ks * 4 + g) ^ cl) * 8)];
            acc2[mt][0] = __builtin_amdgcn_mfma_f32_16x16x32_bf16(pa, bv0, acc2[mt][0], 0, 0, 0);
            acc2[mt][1] = __builtin_amdgcn_mfma_f32_16x16x32_bf16(pa, bv1, acc2[mt][1], 0, 0, 0);
        }
    }

    #pragma unroll
    for (int mt = 0; mt < 8; ++mt)
        #pragma unroll
        for (int n2 = 0; n2 < 2; ++n2)
            #pragma unroll
            for (int r = 0; r < 4; ++r)
                __builtin_nontemporal_store(acc2[mt][n2][r],
                    Og + base + (mt * 16 + g * 4 + r) * E_ + vcol + n2 * 16);
}

extern "C" void kernel_launch(void* const* d_in, const int* in_sizes, int n_in,
                              void* d_out, int out_size, void* d_ws, size_t ws_size,
                              hipStream_t stream) {
    const float* Q = (const float*)d_in[0];
    const float* K = (const float*)d_in[1];
    const float* V = (const float*)d_in[2];
    float* O = (float*)d_out;
    const int b = in_sizes[0] / (T_ * E_);            // 16
    float* A = O + (size_t)b * T_ * E_;               // output #2 region of d_out
    dim3 grid(b * (T_ / BS_));                        // 1024 tiles
    dim3 block(512);
    dba_fused<<<grid, block, 0, stream>>>(Q, K, V, A, O);
}